// Round 19
// baseline (721.022 us; speedup 1.0000x reference)
//
#include <hip/hip_runtime.h>
#include <math.h>

#define MASKN 1023

typedef unsigned short ushort_t;
typedef __attribute__((ext_vector_type(8))) short short8;
typedef __attribute__((ext_vector_type(4))) float floatx4;
typedef __attribute__((ext_vector_type(4))) unsigned short us4v;   // 8B-aligned bf16x4

// tanh-form GELU; v_rcp_f32 instead of IEEE div (R8, ~1ulp, fine for approx gelu)
__device__ __forceinline__ float gelu_f(float x) {
    float x2 = x * x;
    float inner = fmaf(0.044715f * x, x2, x);
    float t = exp2f(inner * -2.302089214f);   // 2^(-2*0.7978845608*log2(e)*inner)
    return x * __builtin_amdgcn_rcpf(1.0f + t);
}

// ---- bf16 storage helpers (compute stays fp32) ----
__device__ __forceinline__ float bf2f(ushort_t h) {
    return __uint_as_float(((unsigned int)h) << 16);
}
__device__ __forceinline__ ushort_t f2bf(float f) {
    unsigned int u = __float_as_uint(f);
    u += 0x7FFFu + ((u >> 16) & 1u);   // round to nearest even
    return (ushort_t)(u >> 16);
}
struct us4 { ushort_t x, y, z, w; };

// pack 2 f32 -> 2 bf16 in ONE v_cvt_pk_bf16_f32 (RNE, same as manual path)
__device__ __forceinline__ unsigned int pk2bf(float lo, float hi) {
    unsigned int r;
    asm("v_cvt_pk_bf16_f32 %0, %1, %2" : "=v"(r) : "v"(lo), "v"(hi));
    return r;
}

__device__ __forceinline__ void st4(ushort_t* p, float4 v) {
    uint2 w;
    w.x = pk2bf(v.x, v.y);
    w.y = pk2bf(v.z, v.w);
    *(uint2*)p = w;
}

// async global->LDS, 16 B per lane; LDS dest = wave-uniform base + lane*16 (HW),
// global src is PER-LANE (this is how the swizzled staging works).
__device__ __forceinline__ void async16(ushort_t* l, const ushort_t* g) {
    __builtin_amdgcn_global_load_lds(
        (const __attribute__((address_space(1))) void*)g,
        (__attribute__((address_space(3))) void*)l, 16, 0, 0);
}

// ---------------- twiddle step table for k_f2 / k_i1
__global__ void k_fill_tw(float* __restrict__ ct, float* __restrict__ st) {
    int j = blockIdx.x * 256 + threadIdx.x;   // 0..1023
    float ang = (float)j * (6.283185307179586f / 1024.0f);
    float s, c;
    sincosf(ang, &s, &c);
    ct[j] = c; st[j] = s;
}

// ---------------- T1 table
__global__ void k_fill_T1(ushort_t* __restrict__ T1h, ushort_t* __restrict__ T1l) {
    int idx = blockIdx.x * 256 + threadIdx.x;   // 0..65535
    int k2p = idx >> 10, y = idx & 1023;
    int k2 = k2p >> 1;
    float ang = (float)((k2 * y) & MASKN) * (6.283185307179586f / 1024.0f);
    float s, c;
    sincosf(ang, &s, &c);
    float v = (k2p & 1) ? -s : c;
    ushort_t h = f2bf(v);
    T1h[idx] = h;
    T1l[idx] = f2bf(v - bf2f(h));
}

// ---------------- T2 table: T2[n2][kk]
__global__ void k_fill_T2(ushort_t* __restrict__ T2h, ushort_t* __restrict__ T2l) {
    int idx = blockIdx.x * 256 + threadIdx.x;   // 0..65535
    int n2 = idx >> 6, kk = idx & 63;
    int k2 = kk >> 1;
    float ang = (float)((k2 * n2) & MASKN) * (6.283185307179586f / 1024.0f);
    float s, c;
    sincosf(ang, &s, &c);
    float v = (kk & 1) ? -s : c;
    ushort_t h = f2bf(v);
    T2h[idx] = h;
    T2l[idx] = f2bf(v - bf2f(h));
}

// ---------------- wT tables: wT[l][d][c] = w_l[c][d], hi/lo
__global__ void k_fill_wT(const float* __restrict__ w1, const float* __restrict__ w2,
        const float* __restrict__ w3, const float* __restrict__ w4,
        ushort_t* __restrict__ wTh, ushort_t* __restrict__ wTl) {
    int l = blockIdx.y;
    int i = blockIdx.x * 256 + threadIdx.x;   // 0..4095
    int d = i >> 6, c = i & 63;
    const float* w = (l == 0) ? w1 : (l == 1) ? w2 : (l == 2) ? w3 : w4;
    float v = w[c * 64 + d];
    ushort_t h = f2bf(v);
    wTh[l * 4096 + i] = h;
    wTl[l * 4096 + i] = f2bf(v - bf2f(h));
}

// ---------------- shallow
__global__ __launch_bounds__(256) void k_shallow(const float* __restrict__ in,
        const float* __restrict__ Wsh, const float* __restrict__ bsh,
        ushort_t* __restrict__ vt) {
    int tid = blockIdx.x * 256 + threadIdx.x;
    int p = tid >> 4, c0 = (tid & 15) << 2;
    float a0 = in[p * 2], a1 = in[p * 2 + 1];
    float4 w0 = *(const float4*)&Wsh[c0];
    float4 w1 = *(const float4*)&Wsh[64 + c0];
    float4 b  = *(const float4*)&bsh[c0];
    float4 r;
    r.x = gelu_f(fmaf(a0, w0.x, fmaf(a1, w1.x, b.x)));
    r.y = gelu_f(fmaf(a0, w0.y, fmaf(a1, w1.y, b.y)));
    r.z = gelu_f(fmaf(a0, w0.z, fmaf(a1, w1.z, b.z)));
    r.w = gelu_f(fmaf(a0, w0.w, fmaf(a1, w1.w, b.w)));
    st4(&vt[(size_t)p * 64 + c0], r);
}

// ---------------- F1 standalone (layer 0 only; R13/R14 x-paired structure)
#define VS1 72   // row stride in shorts (144 B -> 2-way banks = free)
__global__ __launch_bounds__(256, 3) void k_f1(const ushort_t* __restrict__ vt,
        const ushort_t* __restrict__ T1h, const ushort_t* __restrict__ T1l,
        float* __restrict__ gT) {
    __shared__ __align__(16) ushort_t t1s[2][8192];      // [buf][h|l] shorts
    __shared__ __align__(16) ushort_t vs[2][64 * VS1];   // [x][c][y], single-buffered
    int t = threadIdx.x;
    int x0 = blockIdx.x * 2;
    int wv = t >> 6, lane = t & 63;
    int lm = lane & 15, quad = lane >> 4;
    int lrow = t & 63, cq = (t >> 6) * 16;               // staging map: 64 y-rows x 4 c-quarters
    const ushort_t* vrow0 = vt + (size_t)x0 * 65536;
    const ushort_t* vrow1 = vrow0 + 65536;

    floatx4 acc[2][4];
    #pragma unroll
    for (int xi = 0; xi < 2; ++xi)
        #pragma unroll
        for (int nt = 0; nt < 4; ++nt) acc[xi][nt] = (floatx4)(0.f);

    uint4 pf[2][2][2];   // [chunk parity][x][half]; loaded 2 chunks ahead
    #pragma unroll
    for (int i = 0; i < 4; ++i) {
        int j = (wv * 4 + i) * 64 + lane;
        int jj = j & 511;
        int r = jj >> 3, du = jj & 7, su = du ^ (r & 7);
        const ushort_t* src = ((j < 512) ? T1h : T1l) + (size_t)r * 1024 + su * 8;
        async16(&t1s[0][(wv * 4 + i) * 512], src);
    }
    __builtin_amdgcn_sched_barrier(0);
    {
        const ushort_t* s00 = vrow0 + (size_t)lrow * 64 + cq;
        pf[0][0][0] = *(const uint4*)(s00);
        pf[0][0][1] = *(const uint4*)(s00 + 8);
        const ushort_t* s01 = vrow1 + (size_t)lrow * 64 + cq;
        pf[0][1][0] = *(const uint4*)(s01);
        pf[0][1][1] = *(const uint4*)(s01 + 8);
        const ushort_t* s10 = vrow0 + (size_t)(64 + lrow) * 64 + cq;
        pf[1][0][0] = *(const uint4*)(s10);
        pf[1][0][1] = *(const uint4*)(s10 + 8);
        const ushort_t* s11 = vrow1 + (size_t)(64 + lrow) * 64 + cq;
        pf[1][1][0] = *(const uint4*)(s11);
        pf[1][1][1] = *(const uint4*)(s11 + 8);
    }
    __builtin_amdgcn_sched_barrier(0);

    for (int hc = 0; hc < 16; ++hc) {
        int b = hc & 1;
        #pragma unroll
        for (int xi = 0; xi < 2; ++xi)
            #pragma unroll
            for (int i = 0; i < 2; ++i) {
                union { uint4 u; ushort_t e[8]; } uv;
                uv.u = pf[b][xi][i];
                #pragma unroll
                for (int j = 0; j < 8; ++j)
                    vs[xi][(cq + i * 8 + j) * VS1 + lrow] = uv.e[j];
            }
        __builtin_amdgcn_sched_barrier(0);
        if (hc < 15) asm volatile("s_waitcnt vmcnt(4)" ::: "memory");
        else         asm volatile("s_waitcnt vmcnt(0)" ::: "memory");
        __builtin_amdgcn_sched_barrier(0);
        __builtin_amdgcn_s_barrier();   // RAW barrier: no vmcnt(0) drain
        if (hc < 15) {
            #pragma unroll
            for (int i = 0; i < 4; ++i) {
                int j = (wv * 4 + i) * 64 + lane;
                int jj = j & 511;
                int r = jj >> 3, du = jj & 7, su = du ^ (r & 7);
                const ushort_t* src = ((j < 512) ? T1h : T1l)
                                      + (size_t)r * 1024 + (hc + 1) * 64 + su * 8;
                async16(&t1s[b ^ 1][(wv * 4 + i) * 512], src);
            }
        }
        if (hc < 14) {
            const ushort_t* s0 = vrow0 + (size_t)((hc + 2) * 64 + lrow) * 64 + cq;
            pf[b][0][0] = *(const uint4*)(s0);
            pf[b][0][1] = *(const uint4*)(s0 + 8);
            const ushort_t* s1 = vrow1 + (size_t)((hc + 2) * 64 + lrow) * 64 + cq;
            pf[b][1][0] = *(const uint4*)(s1);
            pf[b][1][1] = *(const uint4*)(s1 + 8);
        }
        __builtin_amdgcn_sched_barrier(0);

        #pragma unroll
        for (int ys = 0; ys < 2; ++ys) {
            short8 af0 = *(const short8*)&vs[0][(wv * 16 + lm) * VS1 + ys * 32 + quad * 8];
            short8 af1 = *(const short8*)&vs[1][(wv * 16 + lm) * VS1 + ys * 32 + quad * 8];
            #pragma unroll
            for (int nt = 0; nt < 4; ++nt) {
                int sl = (((ys * 4 + quad) ^ (lm & 7)) * 8);
                short8 bh = *(const short8*)&t1s[b][(nt * 16 + lm) * 64 + sl];
                short8 bl = *(const short8*)&t1s[b][4096 + (nt * 16 + lm) * 64 + sl];
                acc[0][nt] = __builtin_amdgcn_mfma_f32_16x16x32_bf16(af0, bh, acc[0][nt], 0, 0, 0);
                acc[0][nt] = __builtin_amdgcn_mfma_f32_16x16x32_bf16(af0, bl, acc[0][nt], 0, 0, 0);
                acc[1][nt] = __builtin_amdgcn_mfma_f32_16x16x32_bf16(af1, bh, acc[1][nt], 0, 0, 0);
                acc[1][nt] = __builtin_amdgcn_mfma_f32_16x16x32_bf16(af1, bl, acc[1][nt], 0, 0, 0);
            }
        }
    }
    #pragma unroll
    for (int xi = 0; xi < 2; ++xi) {
        float* grow = gT + (size_t)(x0 + xi) * 4096;
        #pragma unroll
        for (int nt = 0; nt < 4; ++nt)
            #pragma unroll
            for (int r = 0; r < 4; ++r)
                grow[(wv * 16 + quad * 4 + r) * 64 + nt * 16 + lm] = acc[xi][nt][r];
    }
}

// ---------------- F2
__global__ __launch_bounds__(256) void k_f2(const float* __restrict__ gT,
        const float* __restrict__ ct, const float* __restrict__ st,
        float* __restrict__ fpr, float* __restrict__ fpi) {
    int t = threadIdx.x;
    int cx = blockIdx.x;
    int cg = blockIdx.y;
    int k10 = blockIdx.z * 8;
    int l = t & 63;
    int q = t >> 6;
    int c = cg * 4 + q;
    int e = l & 1;
    int k2 = l >> 1;
    float acc[8];
    #pragma unroll
    for (int i = 0; i < 8; ++i) acc[i] = 0.f;
    for (int xi = 0; xi < 128; ++xi) {
        int x = cx * 128 + xi;
        float v = gT[(size_t)x * 4096 + c * 64 + l];
        float p = __shfl_xor(v, 1);
        float gr = e ? p : v;
        float gi = e ? v : p;
        float u  = e ? gi : gr;
        float w2 = e ? -gr : gi;
        float cb = ct[x], sb = st[x];
        int ph = (x * k10) & MASKN;
        float cr = ct[ph], sr = st[ph];
        #pragma unroll
        for (int j = 0; j < 8; ++j) {
            acc[j] = fmaf(u, cr, fmaf(w2, sr, acc[j]));
            float nc = fmaf(cr, cb, -sr * sb);
            float ns = fmaf(sr, cb, cr * sb);
            cr = nc; sr = ns;
        }
    }
    float* dst = e ? fpi : fpr;
    #pragma unroll
    for (int j = 0; j < 8; ++j)
        dst[(size_t)cx * 65536 + ((k10 + j) * 32 + k2) * 64 + c] = acc[j];
}

// ---------------- MIX
__global__ __launch_bounds__(64) void k_mix(const float* __restrict__ fpr, const float* __restrict__ fpi,
        const float* __restrict__ Rr, const float* __restrict__ Ri,
        float* __restrict__ Rfr, float* __restrict__ Rfi) {
    __shared__ float fr[64], fi[64];
    int m = blockIdx.x;
    int d = threadIdx.x;
    float sr = 0.f, si = 0.f;
    #pragma unroll
    for (int ch = 0; ch < 8; ++ch) {
        sr += fpr[(size_t)ch * 65536 + m * 64 + d];
        si += fpi[(size_t)ch * 65536 + m * 64 + d];
    }
    fr[d] = sr; fi[d] = si;
    __syncthreads();
    const float* Rrb = Rr + (size_t)m * 4096;
    const float* Rib = Ri + (size_t)m * 4096;
    float ar = 0.f, ai = 0.f;
    for (int c = 0; c < 64; ++c) {
        float rr = Rrb[c * 64 + d], ri = Rib[c * 64 + d];
        ar = fmaf(fr[c], rr, fmaf(-fi[c], ri, ar));
        ai = fmaf(fr[c], ri, fmaf(fi[c], rr, ai));
    }
    Rfr[m * 64 + d] = ar;
    Rfi[m * 64 + d] = ai;
}

// ---------------- I1: Bhl INTERLEAVED layout (R15): block n1's B lives in the
// 16 KB that IS gT row n1 (Bh half at n1*8192 shorts, Bl half at +4096).
__global__ __launch_bounds__(256) void k_i1(const float* __restrict__ Rfr, const float* __restrict__ Rfi,
        const float* __restrict__ ctg, const float* __restrict__ stg,
        ushort_t* __restrict__ Bhl) {
    __shared__ float ct[1024], st[1024];
    int t = threadIdx.x;
    #pragma unroll
    for (int i = 0; i < 4; ++i) { int j = t + 256 * i; ct[j] = ctg[j]; st[j] = stg[j]; }
    __syncthreads();
    int n1 = blockIdx.x;
    int d = t & 63;
    int k20 = (t >> 6) * 8;
    float br[8], bi[8];
    #pragma unroll
    for (int j = 0; j < 8; ++j) { br[j] = 0.f; bi[j] = 0.f; }
    int idx = 0;
    for (int k1 = 0; k1 < 32; ++k1) {
        float cc = ct[idx], ss = st[idx];
        idx = (idx + n1) & MASKN;
        #pragma unroll
        for (int j = 0; j < 8; ++j) {
            float rr = Rfr[(k1 * 32 + k20 + j) * 64 + d];
            float ri = Rfi[(k1 * 32 + k20 + j) * 64 + d];
            br[j] = fmaf(rr, cc, fmaf(-ri, ss, br[j]));
            bi[j] = fmaf(rr, ss, fmaf(ri, cc, bi[j]));
        }
    }
    union { uint4 u[2]; ushort_t e[16]; } hh, ll;
    #pragma unroll
    for (int j = 0; j < 8; ++j) {
        int k2 = k20 + j;
        float sc = (k2 == 0 ? 1.0f : 2.0f) * 9.5367431640625e-7f;   // 1/2^20
        float vr = br[j] * sc, vi = bi[j] * sc;
        ushort_t hr = f2bf(vr), hi2 = f2bf(vi);
        hh.e[2 * j] = hr;          hh.e[2 * j + 1] = hi2;
        ll.e[2 * j] = f2bf(vr - bf2f(hr));
        ll.e[2 * j + 1] = f2bf(vi - bf2f(hi2));
    }
    size_t base = (size_t)n1 * 8192 + d * 64 + 2 * k20;
    *(uint4*)(Bhl + base) = hh.u[0];
    *(uint4*)(Bhl + base + 8) = hh.u[1];
    *(uint4*)(Bhl + 4096 + base) = ll.u[0];
    *(uint4*)(Bhl + 4096 + base + 8) = ll.u[1];
}

// ---------------- I2F (R18, resubmitted after infra failure): fused i2+f1 with
// COALESCED vt stores.  R16/R17 ~105-108 us at 2.1 TB/s combined (6.3 achievable);
// write stream was 67M scattered 8-B stores -> suspected partial-line
// write-combining failure.  Fix: output tile staged into wave-private row-major
// vtile[64][72]; after barrier1 each wave stores its 16 rows as 2x
// global_store_dwordx4 (16 B/lane, full 64-B lines).  t1s/trans single-buffer +
// 2 barriers (R16 scheme, measured equal to R17's 1 barrier).  Per-chunk vmem:
// t1s(4), pf(6) -> vmcnt(6) at barrier1 retires t1s (prior-chunk stores are
// older, auto-covered); stores(2) post-barrier1.
// LDS: ab 32K + t1s 16K + trans 8K + vtile 9K = 66.5K -> 2 blocks/CU.
__global__ __launch_bounds__(256, 2) void k_i2f(ushort_t* __restrict__ vt,
        ushort_t* Bhl,                       // aliases gT -- no restrict
        const ushort_t* __restrict__ T2h, const ushort_t* __restrict__ T2l,
        const ushort_t* __restrict__ wTh, const ushort_t* __restrict__ wTl,
        const ushort_t* __restrict__ T1h, const ushort_t* __restrict__ T1l,
        float* gT) {                         // aliases Bhl -- no restrict
    __shared__ __align__(16) ushort_t ab[16384];        // 32 KB (swizzled B+wT)
    __shared__ __align__(16) ushort_t t1s[8192];        // 16 KB [h|l]
    __shared__ __align__(16) ushort_t trans[4096];      // 8 KB, swizzled [ch][y]
    __shared__ __align__(16) ushort_t vtile[64 * VS1];  // 9 KB row-major [n2][d]
    int t = threadIdx.x;
    int wv = t >> 6, lane = t & 63;
    int lm = lane & 15, quad = lane >> 4;
    int n1 = blockIdx.x;
    const ushort_t* Bhr = Bhl + (size_t)n1 * 8192;
    const ushort_t* Blr = Bhr + 4096;

    // ---- prologue: ab staged; chunk-0 regs prefetched; one full drain
    {
        const ushort_t* s = (wv == 0) ? Bhr : (wv == 1) ? Blr : (wv == 2) ? wTh : wTl;
        #pragma unroll
        for (int i = 0; i < 8; ++i) {
            int j = i * 64 + lane;
            int r = j >> 3, u = (j & 7) ^ (r & 7);
            async16(&ab[wv * 4096 + i * 512], s + r * 64 + u * 8);
        }
    }

    int n2b = wv * 16 + lm;
    const ushort_t* t2hp = T2h + n2b * 64 + quad * 8;
    const ushort_t* t2lp = T2l + n2b * 64 + quad * 8;
    const ushort_t* vrd  = vt + ((size_t)n1 * 1024 + n2b) * 64 + quad * 8;
    ushort_t*       vstw = vt + ((size_t)n1 * 1024 + wv * 16) * 64;   // wave's 16-row base

    short8 th[2][2], tl[2][2], vv[2][2];
    #pragma unroll
    for (int ks = 0; ks < 2; ++ks) {
        th[0][ks] = *(const short8*)(t2hp + ks * 32);
        tl[0][ks] = *(const short8*)(t2lp + ks * 32);
        vv[0][ks] = *(const short8*)(vrd + ks * 32);
    }
    floatx4 facc[4];
    #pragma unroll
    for (int nt = 0; nt < 4; ++nt) facc[nt] = (floatx4)(0.f);
    __syncthreads();   // ab staged + visible (one-time full drain)

    int r7 = lm & 7;
    int u3 = n2b >> 3, e3 = n2b & 7;    // trans scatter unit/elem
    int srow = lane >> 2;               // store map: 16 rows x 4 chunks
    int scol = (lane & 3) * 8;          // 16B chunk offset (shorts)
    #pragma unroll
    for (int c = 0; c < 16; ++c) {
        int b = c & 1;
        // (1) stage t1s for THIS chunk (4 async16; latency covered by i2 below)
        #pragma unroll
        for (int i = 0; i < 4; ++i) {
            int j = (wv * 4 + i) * 64 + lane;
            int jj = j & 511;
            int rr_ = jj >> 3, du = jj & 7, su = du ^ (rr_ & 7);
            const ushort_t* src = ((j < 512) ? T1h : T1l)
                                  + (size_t)rr_ * 1024 + c * 64 + su * 8;
            async16(&t1s[(wv * 4 + i) * 512], src);
        }
        __builtin_amdgcn_sched_barrier(0);
        // (2) i2 prefetch chunk c+1 -- ALWAYS 6 loads (c=15 reads mapped
        // garbage; keeps vmcnt uniform)
        #pragma unroll
        for (int ks = 0; ks < 2; ++ks) {
            th[b ^ 1][ks] = *(const short8*)(t2hp + (c + 1) * 4096 + ks * 32);
            tl[b ^ 1][ks] = *(const short8*)(t2lp + (c + 1) * 4096 + ks * 32);
            vv[b ^ 1][ks] = *(const short8*)(vrd + (size_t)(c + 1) * 4096 + ks * 32);
        }
        __builtin_amdgcn_sched_barrier(0);

        // (3) i2 MFMA (R8 body)
        floatx4 acc[4];
        #pragma unroll
        for (int mt = 0; mt < 4; ++mt) acc[mt] = (floatx4)(0.f);
        __builtin_amdgcn_s_setprio(1);
        #pragma unroll
        for (int ks = 0; ks < 2; ++ks) {
            int sl = ((ks * 4 + quad) ^ r7) * 8;
            #pragma unroll
            for (int mt = 0; mt < 4; ++mt) {
                int ro = (mt * 16 + lm) * 64 + sl;
                short8 ah = *(const short8*)&ab[ro];
                short8 al = *(const short8*)&ab[4096 + ro];
                short8 wh = *(const short8*)&ab[8192 + ro];
                short8 wl = *(const short8*)&ab[12288 + ro];
                acc[mt] = __builtin_amdgcn_mfma_f32_16x16x32_bf16(ah, th[b][ks], acc[mt], 0, 0, 0);
                acc[mt] = __builtin_amdgcn_mfma_f32_16x16x32_bf16(al, th[b][ks], acc[mt], 0, 0, 0);
                acc[mt] = __builtin_amdgcn_mfma_f32_16x16x32_bf16(ah, tl[b][ks], acc[mt], 0, 0, 0);
                acc[mt] = __builtin_amdgcn_mfma_f32_16x16x32_bf16(wh, vv[b][ks], acc[mt], 0, 0, 0);
                acc[mt] = __builtin_amdgcn_mfma_f32_16x16x32_bf16(wl, vv[b][ks], acc[mt], 0, 0, 0);
            }
        }
        __builtin_amdgcn_s_setprio(0);

        // (4) gelu + pack -> vtile (own row, row-major) + trans (swizzled)
        uint2 w[4];
        #pragma unroll
        for (int mt = 0; mt < 4; ++mt) {
            w[mt].x = pk2bf(gelu_f(acc[mt][0]), gelu_f(acc[mt][1]));
            w[mt].y = pk2bf(gelu_f(acc[mt][2]), gelu_f(acc[mt][3]));
            *(uint2*)&vtile[n2b * VS1 + mt * 16 + quad * 4] = w[mt];
        }
        #pragma unroll
        for (int mt = 0; mt < 4; ++mt) {
            int chb = mt * 16 + quad * 4;
            #pragma unroll
            for (int r = 0; r < 4; ++r) {
                int ch = chb + r;
                ushort_t val = (r == 0) ? (ushort_t)(w[mt].x & 0xffffu)
                             : (r == 1) ? (ushort_t)(w[mt].x >> 16)
                             : (r == 2) ? (ushort_t)(w[mt].y & 0xffffu)
                                        : (ushort_t)(w[mt].y >> 16);
                trans[ch * 64 + ((u3 ^ (ch & 7)) << 3) + e3] = val;
            }
        }
        __builtin_amdgcn_sched_barrier(0);
        // (5) waits + barrier1: trans/vtile visible (lgkm); t1s complete
        // (newer vmem = pf 6 only; prior-chunk stores are older -> also done)
        asm volatile("s_waitcnt lgkmcnt(0)" ::: "memory");
        asm volatile("s_waitcnt vmcnt(6)" ::: "memory");
        __builtin_amdgcn_sched_barrier(0);
        __builtin_amdgcn_s_barrier();   // barrier1
        __builtin_amdgcn_sched_barrier(0);

        // (6) COALESCED vt store: wave's 16 rows, 16 B/lane, 2 instructions
        #pragma unroll
        for (int s = 0; s < 2; ++s) {
            uint4 d4 = *(const uint4*)&vtile[(wv * 16 + srow) * VS1 + scol + s * 32];
            *(uint4*)(vstw + (size_t)c * 4096 + srow * 64 + scol + s * 32) = d4;
        }
        __builtin_amdgcn_sched_barrier(0);

        // (7) f1 MFMA: A = trans rows wv*16..+16 (swizzled), B = t1s
        #pragma unroll
        for (int ys = 0; ys < 2; ++ys) {
            int ch = wv * 16 + lm;
            short8 af = *(const short8*)&trans[ch * 64 + (((ys * 4 + quad) ^ (ch & 7)) << 3)];
            #pragma unroll
            for (int nt = 0; nt < 4; ++nt) {
                int sl = ((ys * 4 + quad) ^ r7) * 8;
                short8 bh = *(const short8*)&t1s[(nt * 16 + lm) * 64 + sl];
                short8 bl = *(const short8*)&t1s[4096 + (nt * 16 + lm) * 64 + sl];
                facc[nt] = __builtin_amdgcn_mfma_f32_16x16x32_bf16(af, bh, facc[nt], 0, 0, 0);
                facc[nt] = __builtin_amdgcn_mfma_f32_16x16x32_bf16(af, bl, facc[nt], 0, 0, 0);
            }
        }
        __builtin_amdgcn_sched_barrier(0);
        __builtin_amdgcn_s_barrier();   // barrier2: reads done before re-stage/rewrite
        __builtin_amdgcn_sched_barrier(0);
    }

    // ---- epilogue: gT row n1 (overwrites this block's own Bhl slot; WAR safe)
    float* grow = gT + (size_t)n1 * 4096;
    #pragma unroll
    for (int nt = 0; nt < 4; ++nt)
        #pragma unroll
        for (int r = 0; r < 4; ++r)
            grow[(wv * 16 + quad * 4 + r) * 64 + nt * 16 + lm] = facc[nt][r];
}

// ---------------- I2 final (R8 structure + fused projection; interleaved Bhl)
__global__ __launch_bounds__(256, 4) void k_i2fin(ushort_t* __restrict__ vt,
        const ushort_t* __restrict__ Bhl,
        const ushort_t* __restrict__ T2h, const ushort_t* __restrict__ T2l,
        const ushort_t* __restrict__ wTh, const ushort_t* __restrict__ wTl,
        const float* __restrict__ Wp, const float* __restrict__ bp,
        float* __restrict__ out) {
    __shared__ __align__(16) ushort_t ab[16384];
    int t = threadIdx.x;
    int wv = t >> 6, lane = t & 63;
    int lm = lane & 15, quad = lane >> 4;
    int n1 = blockIdx.x;
    const ushort_t* Bhr = Bhl + (size_t)n1 * 8192;
    const ushort_t* Blr = Bhr + 4096;
    {
        const ushort_t* s = (wv == 0) ? Bhr : (wv == 1) ? Blr : (wv == 2) ? wTh : wTl;
        #pragma unroll
        for (int i = 0; i < 8; ++i) {
            int j = i * 64 + lane;
            int r = j >> 3, u = (j & 7) ^ (r & 7);
            async16(&ab[wv * 4096 + i * 512], s + r * 64 + u * 8);
        }
    }
    int n2b = wv * 16 + lm;
    const ushort_t* t2hp = T2h + n2b * 64 + quad * 8;
    const ushort_t* t2lp = T2l + n2b * 64 + quad * 8;
    const ushort_t* vrd  = vt + ((size_t)n1 * 1024 + n2b) * 64 + quad * 8;
    short8 th[2][2], tl[2][2], vv[2][2];
    #pragma unroll
    for (int ks = 0; ks < 2; ++ks) {
        th[0][ks] = *(const short8*)(t2hp + ks * 32);
        tl[0][ks] = *(const short8*)(t2lp + ks * 32);
        vv[0][ks] = *(const short8*)(vrd + ks * 32);
    }
    float4 wpv[4];
    float bp0 = bp[0];
    #pragma unroll
    for (int mt = 0; mt < 4; ++mt) wpv[mt] = *(const float4*)&Wp[mt * 16 + quad * 4];
    __syncthreads();

    int r7 = lm & 7;
    #pragma unroll
    for (int c = 0; c < 16; ++c) {
        if (c < 15) {
            #pragma unroll
            for (int ks = 0; ks < 2; ++ks) {
                th[(c + 1) & 1][ks] = *(const short8*)(t2hp + (c + 1) * 4096 + ks * 32);
                tl[(c + 1) & 1][ks] = *(const short8*)(t2lp + (c + 1) * 4096 + ks * 32);
                vv[(c + 1) & 1][ks] = *(const short8*)(vrd + (size_t)(c + 1) * 4096 + ks * 32);
            }
        }
        __builtin_amdgcn_sched_barrier(0);
        floatx4 acc[4];
        #pragma unroll
        for (int mt = 0; mt < 4; ++mt) acc[mt] = (floatx4)(0.f);
        __builtin_amdgcn_s_setprio(1);
        #pragma unroll
        for (int ks = 0; ks < 2; ++ks) {
            int sl = ((ks * 4 + quad) ^ r7) * 8;
            #pragma unroll
            for (int mt = 0; mt < 4; ++mt) {
                int ro = (mt * 16 + lm) * 64 + sl;
                short8 ah = *(const short8*)&ab[ro];
                short8 al = *(const short8*)&ab[4096 + ro];
                short8 wh = *(const short8*)&ab[8192 + ro];
                short8 wl = *(const short8*)&ab[12288 + ro];
                acc[mt] = __builtin_amdgcn_mfma_f32_16x16x32_bf16(ah, th[c & 1][ks], acc[mt], 0, 0, 0);
                acc[mt] = __builtin_amdgcn_mfma_f32_16x16x32_bf16(al, th[c & 1][ks], acc[mt], 0, 0, 0);
                acc[mt] = __builtin_amdgcn_mfma_f32_16x16x32_bf16(ah, tl[c & 1][ks], acc[mt], 0, 0, 0);
                acc[mt] = __builtin_amdgcn_mfma_f32_16x16x32_bf16(wh, vv[c & 1][ks], acc[mt], 0, 0, 0);
                acc[mt] = __builtin_amdgcn_mfma_f32_16x16x32_bf16(wl, vv[c & 1][ks], acc[mt], 0, 0, 0);
            }
        }
        __builtin_amdgcn_s_setprio(0);
        float s = 0.f;
        #pragma unroll
        for (int mt = 0; mt < 4; ++mt) {
            s = fmaf(gelu_f(acc[mt][0]), wpv[mt].x, s);
            s = fmaf(gelu_f(acc[mt][1]), wpv[mt].y, s);
            s = fmaf(gelu_f(acc[mt][2]), wpv[mt].z, s);
            s = fmaf(gelu_f(acc[mt][3]), wpv[mt].w, s);
        }
        s += __shfl_xor(s, 16);
        s += __shfl_xor(s, 32);
        if (quad == 0)
            out[(size_t)n1 * 1024 + c * 64 + n2b] = s + bp0;
    }
}

extern "C" void kernel_launch(void* const* d_in, const int* in_sizes, int n_in,
                              void* d_out, int out_size, void* d_ws, size_t ws_size,
                              hipStream_t stream) {
    const float* in  = (const float*)d_in[0];
    const float* Wsh = (const float*)d_in[1];
    const float* bsh = (const float*)d_in[2];
    const float* Wp  = (const float*)d_in[15];
    const float* bp  = (const float*)d_in[16];

    // workspace layout (~151.9 MB, proven to fit)
    char* wsb = (char*)d_ws;
    ushort_t* vt   = (ushort_t*)wsb;                          // 134,217,728 B
    float* ctab = (float*)(wsb + 134217728);                  // 1024
    float* stab = ctab + 1024;                                // 1024
    float* gT   = stab + 1024;                                // 16 MB (rows interleave with Bhl)
    float* Rfr  = gT + 4194304;                               // 65536
    float* Rfi  = Rfr + 65536;                                // 65536
    ushort_t* T1h = (ushort_t*)(Rfi + 65536);                 // 64*1024
    ushort_t* T1l = T1h + 65536;
    ushort_t* T2h = T1l + 65536;                              // 1024*64
    ushort_t* T2l = T2h + 65536;
    ushort_t* wTh = T2l + 65536;                              // 4*64*64
    ushort_t* wTl = wTh + 16384;
    ushort_t* Bhl = (ushort_t*)gT;                            // interleaved with gT rows
    float* fpr = (float*)d_out;                               // alias d_out
    float* fpi = fpr + 524288;

    k_fill_tw<<<4, 256, 0, stream>>>(ctab, stab);
    k_fill_T1<<<256, 256, 0, stream>>>(T1h, T1l);
    k_fill_T2<<<256, 256, 0, stream>>>(T2h, T2l);
    k_fill_wT<<<dim3(16, 4), 256, 0, stream>>>((const float*)d_in[5], (const float*)d_in[8],
                                               (const float*)d_in[11], (const float*)d_in[14], wTh, wTl);
    k_shallow<<<65536, 256, 0, stream>>>(in, Wsh, bsh, vt);
    k_f1<<<512, 256, 0, stream>>>(vt, T1h, T1l, gT);          // layer-0 forward transform
    for (int L = 0; L < 4; ++L) {
        const float* Rr = (const float*)d_in[3 + L * 3];
        const float* Ri = (const float*)d_in[4 + L * 3];
        k_f2<<<dim3(8, 16, 4), 256, 0, stream>>>(gT, ctab, stab, fpr, fpi);
        k_mix<<<1024, 64, 0, stream>>>(fpr, fpi, Rr, Ri, Rfr, Rfi);
        k_i1<<<1024, 256, 0, stream>>>(Rfr, Rfi, ctab, stab, Bhl);
        if (L < 3) {
            // fused inverse + skip + NEXT layer's forward transform
            k_i2f<<<1024, 256, 0, stream>>>(vt, Bhl, T2h, T2l,
                    wTh + L * 4096, wTl + L * 4096, T1h, T1l, gT);
        } else {
            k_i2fin<<<1024, 256, 0, stream>>>(vt, Bhl, T2h, T2l,
                    wTh + L * 4096, wTl + L * 4096, Wp, bp, (float*)d_out);
        }
    }
}

// Round 21
// 711.655 us; speedup vs baseline: 1.0132x; 1.0132x over previous
//
#include <hip/hip_runtime.h>
#include <math.h>

#define MASKN 1023

typedef unsigned short ushort_t;
typedef __attribute__((ext_vector_type(8))) short short8;
typedef __attribute__((ext_vector_type(4))) float floatx4;
typedef __attribute__((ext_vector_type(4))) unsigned short us4v;   // 8B-aligned bf16x4

// tanh-form GELU; v_rcp_f32 instead of IEEE div (R8, ~1ulp, fine for approx gelu)
__device__ __forceinline__ float gelu_f(float x) {
    float x2 = x * x;
    float inner = fmaf(0.044715f * x, x2, x);
    float t = exp2f(inner * -2.302089214f);   // 2^(-2*0.7978845608*log2(e)*inner)
    return x * __builtin_amdgcn_rcpf(1.0f + t);
}

// ---- bf16 storage helpers (compute stays fp32) ----
__device__ __forceinline__ float bf2f(ushort_t h) {
    return __uint_as_float(((unsigned int)h) << 16);
}
__device__ __forceinline__ ushort_t f2bf(float f) {
    unsigned int u = __float_as_uint(f);
    u += 0x7FFFu + ((u >> 16) & 1u);   // round to nearest even
    return (ushort_t)(u >> 16);
}
struct us4 { ushort_t x, y, z, w; };

// pack 2 f32 -> 2 bf16 in ONE v_cvt_pk_bf16_f32 (RNE, same as manual path)
__device__ __forceinline__ unsigned int pk2bf(float lo, float hi) {
    unsigned int r;
    asm("v_cvt_pk_bf16_f32 %0, %1, %2" : "=v"(r) : "v"(lo), "v"(hi));
    return r;
}

__device__ __forceinline__ void st4(ushort_t* p, float4 v) {
    uint2 w;
    w.x = pk2bf(v.x, v.y);
    w.y = pk2bf(v.z, v.w);
    *(uint2*)p = w;
}

// async global->LDS, 16 B per lane; LDS dest = wave-uniform base + lane*16 (HW),
// global src is PER-LANE (this is how the swizzled staging works).
__device__ __forceinline__ void async16(ushort_t* l, const ushort_t* g) {
    __builtin_amdgcn_global_load_lds(
        (const __attribute__((address_space(1))) void*)g,
        (__attribute__((address_space(3))) void*)l, 16, 0, 0);
}

// ---------------- twiddle step table for k_f2 / k_i1
__global__ void k_fill_tw(float* __restrict__ ct, float* __restrict__ st) {
    int j = blockIdx.x * 256 + threadIdx.x;   // 0..1023
    float ang = (float)j * (6.283185307179586f / 1024.0f);
    float s, c;
    sincosf(ang, &s, &c);
    ct[j] = c; st[j] = s;
}

// ---------------- T1 table
__global__ void k_fill_T1(ushort_t* __restrict__ T1h, ushort_t* __restrict__ T1l) {
    int idx = blockIdx.x * 256 + threadIdx.x;   // 0..65535
    int k2p = idx >> 10, y = idx & 1023;
    int k2 = k2p >> 1;
    float ang = (float)((k2 * y) & MASKN) * (6.283185307179586f / 1024.0f);
    float s, c;
    sincosf(ang, &s, &c);
    float v = (k2p & 1) ? -s : c;
    ushort_t h = f2bf(v);
    T1h[idx] = h;
    T1l[idx] = f2bf(v - bf2f(h));
}

// ---------------- T2 table: T2[n2][kk]
__global__ void k_fill_T2(ushort_t* __restrict__ T2h, ushort_t* __restrict__ T2l) {
    int idx = blockIdx.x * 256 + threadIdx.x;   // 0..65535
    int n2 = idx >> 6, kk = idx & 63;
    int k2 = kk >> 1;
    float ang = (float)((k2 * n2) & MASKN) * (6.283185307179586f / 1024.0f);
    float s, c;
    sincosf(ang, &s, &c);
    float v = (kk & 1) ? -s : c;
    ushort_t h = f2bf(v);
    T2h[idx] = h;
    T2l[idx] = f2bf(v - bf2f(h));
}

// ---------------- wT tables: wT[l][d][c] = w_l[c][d], hi/lo
__global__ void k_fill_wT(const float* __restrict__ w1, const float* __restrict__ w2,
        const float* __restrict__ w3, const float* __restrict__ w4,
        ushort_t* __restrict__ wTh, ushort_t* __restrict__ wTl) {
    int l = blockIdx.y;
    int i = blockIdx.x * 256 + threadIdx.x;   // 0..4095
    int d = i >> 6, c = i & 63;
    const float* w = (l == 0) ? w1 : (l == 1) ? w2 : (l == 2) ? w3 : w4;
    float v = w[c * 64 + d];
    ushort_t h = f2bf(v);
    wTh[l * 4096 + i] = h;
    wTl[l * 4096 + i] = f2bf(v - bf2f(h));
}

// ---------------- shallow
__global__ __launch_bounds__(256) void k_shallow(const float* __restrict__ in,
        const float* __restrict__ Wsh, const float* __restrict__ bsh,
        ushort_t* __restrict__ vt) {
    int tid = blockIdx.x * 256 + threadIdx.x;
    int p = tid >> 4, c0 = (tid & 15) << 2;
    float a0 = in[p * 2], a1 = in[p * 2 + 1];
    float4 w0 = *(const float4*)&Wsh[c0];
    float4 w1 = *(const float4*)&Wsh[64 + c0];
    float4 b  = *(const float4*)&bsh[c0];
    float4 r;
    r.x = gelu_f(fmaf(a0, w0.x, fmaf(a1, w1.x, b.x)));
    r.y = gelu_f(fmaf(a0, w0.y, fmaf(a1, w1.y, b.y)));
    r.z = gelu_f(fmaf(a0, w0.z, fmaf(a1, w1.z, b.z)));
    r.w = gelu_f(fmaf(a0, w0.w, fmaf(a1, w1.w, b.w)));
    st4(&vt[(size_t)p * 64 + c0], r);
}

// ---------------- F1 standalone (layer 0 only; R13/R14 x-paired structure)
#define VS1 72   // row stride in shorts (144 B -> 2-way banks = free)
__global__ __launch_bounds__(256, 3) void k_f1(const ushort_t* __restrict__ vt,
        const ushort_t* __restrict__ T1h, const ushort_t* __restrict__ T1l,
        float* __restrict__ gT) {
    __shared__ __align__(16) ushort_t t1s[2][8192];      // [buf][h|l] shorts
    __shared__ __align__(16) ushort_t vs[2][64 * VS1];   // [x][c][y], single-buffered
    int t = threadIdx.x;
    int x0 = blockIdx.x * 2;
    int wv = t >> 6, lane = t & 63;
    int lm = lane & 15, quad = lane >> 4;
    int lrow = t & 63, cq = (t >> 6) * 16;               // staging map: 64 y-rows x 4 c-quarters
    const ushort_t* vrow0 = vt + (size_t)x0 * 65536;
    const ushort_t* vrow1 = vrow0 + 65536;

    floatx4 acc[2][4];
    #pragma unroll
    for (int xi = 0; xi < 2; ++xi)
        #pragma unroll
        for (int nt = 0; nt < 4; ++nt) acc[xi][nt] = (floatx4)(0.f);

    uint4 pf[2][2][2];   // [chunk parity][x][half]; loaded 2 chunks ahead
    #pragma unroll
    for (int i = 0; i < 4; ++i) {
        int j = (wv * 4 + i) * 64 + lane;
        int jj = j & 511;
        int r = jj >> 3, du = jj & 7, su = du ^ (r & 7);
        const ushort_t* src = ((j < 512) ? T1h : T1l) + (size_t)r * 1024 + su * 8;
        async16(&t1s[0][(wv * 4 + i) * 512], src);
    }
    __builtin_amdgcn_sched_barrier(0);
    {
        const ushort_t* s00 = vrow0 + (size_t)lrow * 64 + cq;
        pf[0][0][0] = *(const uint4*)(s00);
        pf[0][0][1] = *(const uint4*)(s00 + 8);
        const ushort_t* s01 = vrow1 + (size_t)lrow * 64 + cq;
        pf[0][1][0] = *(const uint4*)(s01);
        pf[0][1][1] = *(const uint4*)(s01 + 8);
        const ushort_t* s10 = vrow0 + (size_t)(64 + lrow) * 64 + cq;
        pf[1][0][0] = *(const uint4*)(s10);
        pf[1][0][1] = *(const uint4*)(s10 + 8);
        const ushort_t* s11 = vrow1 + (size_t)(64 + lrow) * 64 + cq;
        pf[1][1][0] = *(const uint4*)(s11);
        pf[1][1][1] = *(const uint4*)(s11 + 8);
    }
    __builtin_amdgcn_sched_barrier(0);

    for (int hc = 0; hc < 16; ++hc) {
        int b = hc & 1;
        #pragma unroll
        for (int xi = 0; xi < 2; ++xi)
            #pragma unroll
            for (int i = 0; i < 2; ++i) {
                union { uint4 u; ushort_t e[8]; } uv;
                uv.u = pf[b][xi][i];
                #pragma unroll
                for (int j = 0; j < 8; ++j)
                    vs[xi][(cq + i * 8 + j) * VS1 + lrow] = uv.e[j];
            }
        __builtin_amdgcn_sched_barrier(0);
        if (hc < 15) asm volatile("s_waitcnt vmcnt(4)" ::: "memory");
        else         asm volatile("s_waitcnt vmcnt(0)" ::: "memory");
        __builtin_amdgcn_sched_barrier(0);
        __builtin_amdgcn_s_barrier();   // RAW barrier: no vmcnt(0) drain
        if (hc < 15) {
            #pragma unroll
            for (int i = 0; i < 4; ++i) {
                int j = (wv * 4 + i) * 64 + lane;
                int jj = j & 511;
                int r = jj >> 3, du = jj & 7, su = du ^ (r & 7);
                const ushort_t* src = ((j < 512) ? T1h : T1l)
                                      + (size_t)r * 1024 + (hc + 1) * 64 + su * 8;
                async16(&t1s[b ^ 1][(wv * 4 + i) * 512], src);
            }
        }
        if (hc < 14) {
            const ushort_t* s0 = vrow0 + (size_t)((hc + 2) * 64 + lrow) * 64 + cq;
            pf[b][0][0] = *(const uint4*)(s0);
            pf[b][0][1] = *(const uint4*)(s0 + 8);
            const ushort_t* s1 = vrow1 + (size_t)((hc + 2) * 64 + lrow) * 64 + cq;
            pf[b][1][0] = *(const uint4*)(s1);
            pf[b][1][1] = *(const uint4*)(s1 + 8);
        }
        __builtin_amdgcn_sched_barrier(0);

        #pragma unroll
        for (int ys = 0; ys < 2; ++ys) {
            short8 af0 = *(const short8*)&vs[0][(wv * 16 + lm) * VS1 + ys * 32 + quad * 8];
            short8 af1 = *(const short8*)&vs[1][(wv * 16 + lm) * VS1 + ys * 32 + quad * 8];
            #pragma unroll
            for (int nt = 0; nt < 4; ++nt) {
                int sl = (((ys * 4 + quad) ^ (lm & 7)) * 8);
                short8 bh = *(const short8*)&t1s[b][(nt * 16 + lm) * 64 + sl];
                short8 bl = *(const short8*)&t1s[b][4096 + (nt * 16 + lm) * 64 + sl];
                acc[0][nt] = __builtin_amdgcn_mfma_f32_16x16x32_bf16(af0, bh, acc[0][nt], 0, 0, 0);
                acc[0][nt] = __builtin_amdgcn_mfma_f32_16x16x32_bf16(af0, bl, acc[0][nt], 0, 0, 0);
                acc[1][nt] = __builtin_amdgcn_mfma_f32_16x16x32_bf16(af1, bh, acc[1][nt], 0, 0, 0);
                acc[1][nt] = __builtin_amdgcn_mfma_f32_16x16x32_bf16(af1, bl, acc[1][nt], 0, 0, 0);
            }
        }
    }
    #pragma unroll
    for (int xi = 0; xi < 2; ++xi) {
        float* grow = gT + (size_t)(x0 + xi) * 4096;
        #pragma unroll
        for (int nt = 0; nt < 4; ++nt)
            #pragma unroll
            for (int r = 0; r < 4; ++r)
                grow[(wv * 16 + quad * 4 + r) * 64 + nt * 16 + lm] = acc[xi][nt][r];
    }
}

// ---------------- F2
__global__ __launch_bounds__(256) void k_f2(const float* __restrict__ gT,
        const float* __restrict__ ct, const float* __restrict__ st,
        float* __restrict__ fpr, float* __restrict__ fpi) {
    int t = threadIdx.x;
    int cx = blockIdx.x;
    int cg = blockIdx.y;
    int k10 = blockIdx.z * 8;
    int l = t & 63;
    int q = t >> 6;
    int c = cg * 4 + q;
    int e = l & 1;
    int k2 = l >> 1;
    float acc[8];
    #pragma unroll
    for (int i = 0; i < 8; ++i) acc[i] = 0.f;
    for (int xi = 0; xi < 128; ++xi) {
        int x = cx * 128 + xi;
        float v = gT[(size_t)x * 4096 + c * 64 + l];
        float p = __shfl_xor(v, 1);
        float gr = e ? p : v;
        float gi = e ? v : p;
        float u  = e ? gi : gr;
        float w2 = e ? -gr : gi;
        float cb = ct[x], sb = st[x];
        int ph = (x * k10) & MASKN;
        float cr = ct[ph], sr = st[ph];
        #pragma unroll
        for (int j = 0; j < 8; ++j) {
            acc[j] = fmaf(u, cr, fmaf(w2, sr, acc[j]));
            float nc = fmaf(cr, cb, -sr * sb);
            float ns = fmaf(sr, cb, cr * sb);
            cr = nc; sr = ns;
        }
    }
    float* dst = e ? fpi : fpr;
    #pragma unroll
    for (int j = 0; j < 8; ++j)
        dst[(size_t)cx * 65536 + ((k10 + j) * 32 + k2) * 64 + c] = acc[j];
}

// ---------------- MIX
__global__ __launch_bounds__(64) void k_mix(const float* __restrict__ fpr, const float* __restrict__ fpi,
        const float* __restrict__ Rr, const float* __restrict__ Ri,
        float* __restrict__ Rfr, float* __restrict__ Rfi) {
    __shared__ float fr[64], fi[64];
    int m = blockIdx.x;
    int d = threadIdx.x;
    float sr = 0.f, si = 0.f;
    #pragma unroll
    for (int ch = 0; ch < 8; ++ch) {
        sr += fpr[(size_t)ch * 65536 + m * 64 + d];
        si += fpi[(size_t)ch * 65536 + m * 64 + d];
    }
    fr[d] = sr; fi[d] = si;
    __syncthreads();
    const float* Rrb = Rr + (size_t)m * 4096;
    const float* Rib = Ri + (size_t)m * 4096;
    float ar = 0.f, ai = 0.f;
    for (int c = 0; c < 64; ++c) {
        float rr = Rrb[c * 64 + d], ri = Rib[c * 64 + d];
        ar = fmaf(fr[c], rr, fmaf(-fi[c], ri, ar));
        ai = fmaf(fr[c], ri, fmaf(fi[c], rr, ai));
    }
    Rfr[m * 64 + d] = ar;
    Rfi[m * 64 + d] = ai;
}

// ---------------- I1: Bhl INTERLEAVED layout (R15): block n1's B lives in the
// 16 KB that IS gT row n1 (Bh half at n1*8192 shorts, Bl half at +4096).
__global__ __launch_bounds__(256) void k_i1(const float* __restrict__ Rfr, const float* __restrict__ Rfi,
        const float* __restrict__ ctg, const float* __restrict__ stg,
        ushort_t* __restrict__ Bhl) {
    __shared__ float ct[1024], st[1024];
    int t = threadIdx.x;
    #pragma unroll
    for (int i = 0; i < 4; ++i) { int j = t + 256 * i; ct[j] = ctg[j]; st[j] = stg[j]; }
    __syncthreads();
    int n1 = blockIdx.x;
    int d = t & 63;
    int k20 = (t >> 6) * 8;
    float br[8], bi[8];
    #pragma unroll
    for (int j = 0; j < 8; ++j) { br[j] = 0.f; bi[j] = 0.f; }
    int idx = 0;
    for (int k1 = 0; k1 < 32; ++k1) {
        float cc = ct[idx], ss = st[idx];
        idx = (idx + n1) & MASKN;
        #pragma unroll
        for (int j = 0; j < 8; ++j) {
            float rr = Rfr[(k1 * 32 + k20 + j) * 64 + d];
            float ri = Rfi[(k1 * 32 + k20 + j) * 64 + d];
            br[j] = fmaf(rr, cc, fmaf(-ri, ss, br[j]));
            bi[j] = fmaf(rr, ss, fmaf(ri, cc, bi[j]));
        }
    }
    union { uint4 u[2]; ushort_t e[16]; } hh, ll;
    #pragma unroll
    for (int j = 0; j < 8; ++j) {
        int k2 = k20 + j;
        float sc = (k2 == 0 ? 1.0f : 2.0f) * 9.5367431640625e-7f;   // 1/2^20
        float vr = br[j] * sc, vi = bi[j] * sc;
        ushort_t hr = f2bf(vr), hi2 = f2bf(vi);
        hh.e[2 * j] = hr;          hh.e[2 * j + 1] = hi2;
        ll.e[2 * j] = f2bf(vr - bf2f(hr));
        ll.e[2 * j + 1] = f2bf(vi - bf2f(hi2));
    }
    size_t base = (size_t)n1 * 8192 + d * 64 + 2 * k20;
    *(uint4*)(Bhl + base) = hh.u[0];
    *(uint4*)(Bhl + base + 8) = hh.u[1];
    *(uint4*)(Bhl + 4096 + base) = ll.u[0];
    *(uint4*)(Bhl + 4096 + base + 8) = ll.u[1];
}

// ---------------- I2F: EXACT R16 configuration (best measured total: 714.8 us).
// Fused i2 + next layer's f1.  Three structural variants measured 105-110 us
// (R16 2-barrier/scattered=105, R17 1-barrier/0-conflict=108, R19 coalesced
// stores=110): the kernel is bound by its serial per-chunk dependency chain
// (i2 MFMA -> gelu -> scatter -> rendezvous -> f1 MFMA on same chunk's data),
// not by barriers, bank conflicts, or store pattern.  R16 is the optimum.
// Counted-vmcnt: issue order per chunk = t1s(4), pf(6), stores(4); vmcnt(10)
// at barrier1 completes t1s while leaving pf+stores in flight (last chunk: 4).
// LDS: ab 32K + t1s 16K + trans 9K = 57K -> 2 blocks/CU.
__global__ __launch_bounds__(256, 2) void k_i2f(ushort_t* __restrict__ vt,
        ushort_t* Bhl,                       // aliases gT -- no restrict
        const ushort_t* __restrict__ T2h, const ushort_t* __restrict__ T2l,
        const ushort_t* __restrict__ wTh, const ushort_t* __restrict__ wTl,
        const ushort_t* __restrict__ T1h, const ushort_t* __restrict__ T1l,
        float* gT) {                         // aliases Bhl -- no restrict
    __shared__ __align__(16) ushort_t ab[16384];       // 32 KB (swizzled B+wT)
    __shared__ __align__(16) ushort_t t1s[8192];       // 16 KB [h|l] for chunk c
    __shared__ __align__(16) ushort_t trans[64 * VS1]; // 9 KB [ch][y]
    int t = threadIdx.x;
    int wv = t >> 6, lane = t & 63;
    int lm = lane & 15, quad = lane >> 4;
    int n1 = blockIdx.x;
    const ushort_t* Bhr = Bhl + (size_t)n1 * 8192;
    const ushort_t* Blr = Bhr + 4096;

    // ---- stage A-side into LDS once (R8 swizzle pattern)
    {
        const ushort_t* s = (wv == 0) ? Bhr : (wv == 1) ? Blr : (wv == 2) ? wTh : wTl;
        #pragma unroll
        for (int i = 0; i < 8; ++i) {
            int j = i * 64 + lane;
            int r = j >> 3, u = (j & 7) ^ (r & 7);
            async16(&ab[wv * 4096 + i * 512], s + r * 64 + u * 8);
        }
    }

    int n2b = wv * 16 + lm;
    const ushort_t* t2hp = T2h + n2b * 64 + quad * 8;
    const ushort_t* t2lp = T2l + n2b * 64 + quad * 8;
    const ushort_t* vrd  = vt + ((size_t)n1 * 1024 + n2b) * 64 + quad * 8;
    ushort_t*       vst  = vt + ((size_t)n1 * 1024 + n2b) * 64;

    short8 th[2][2], tl[2][2], vv[2][2];
    #pragma unroll
    for (int ks = 0; ks < 2; ++ks) {
        th[0][ks] = *(const short8*)(t2hp + ks * 32);
        tl[0][ks] = *(const short8*)(t2lp + ks * 32);
        vv[0][ks] = *(const short8*)(vrd + ks * 32);
    }
    floatx4 facc[4];
    #pragma unroll
    for (int nt = 0; nt < 4; ++nt) facc[nt] = (floatx4)(0.f);
    __syncthreads();   // prologue: ab staged + visible (one-time full drain)

    int r7 = lm & 7;
    #pragma unroll
    for (int c = 0; c < 16; ++c) {
        // (1) stage t1s for THIS chunk c (latency covered by i2 phase below)
        #pragma unroll
        for (int i = 0; i < 4; ++i) {
            int j = (wv * 4 + i) * 64 + lane;
            int jj = j & 511;
            int rr_ = jj >> 3, du = jj & 7, su = du ^ (rr_ & 7);
            const ushort_t* src = ((j < 512) ? T1h : T1l)
                                  + (size_t)rr_ * 1024 + c * 64 + su * 8;
            async16(&t1s[(wv * 4 + i) * 512], src);
        }
        __builtin_amdgcn_sched_barrier(0);
        // (2) i2 prefetch chunk c+1
        if (c < 15) {
            #pragma unroll
            for (int ks = 0; ks < 2; ++ks) {
                th[(c + 1) & 1][ks] = *(const short8*)(t2hp + (c + 1) * 4096 + ks * 32);
                tl[(c + 1) & 1][ks] = *(const short8*)(t2lp + (c + 1) * 4096 + ks * 32);
                vv[(c + 1) & 1][ks] = *(const short8*)(vrd + (size_t)(c + 1) * 4096 + ks * 32);
            }
        }
        __builtin_amdgcn_sched_barrier(0);

        // (3) i2 MFMA (R8 body)
        floatx4 acc[4];
        #pragma unroll
        for (int mt = 0; mt < 4; ++mt) acc[mt] = (floatx4)(0.f);
        __builtin_amdgcn_s_setprio(1);
        #pragma unroll
        for (int ks = 0; ks < 2; ++ks) {
            int sl = ((ks * 4 + quad) ^ r7) * 8;
            #pragma unroll
            for (int mt = 0; mt < 4; ++mt) {
                int ro = (mt * 16 + lm) * 64 + sl;
                short8 ah = *(const short8*)&ab[ro];
                short8 al = *(const short8*)&ab[4096 + ro];
                short8 wh = *(const short8*)&ab[8192 + ro];
                short8 wl = *(const short8*)&ab[12288 + ro];
                acc[mt] = __builtin_amdgcn_mfma_f32_16x16x32_bf16(ah, th[c & 1][ks], acc[mt], 0, 0, 0);
                acc[mt] = __builtin_amdgcn_mfma_f32_16x16x32_bf16(al, th[c & 1][ks], acc[mt], 0, 0, 0);
                acc[mt] = __builtin_amdgcn_mfma_f32_16x16x32_bf16(ah, tl[c & 1][ks], acc[mt], 0, 0, 0);
                acc[mt] = __builtin_amdgcn_mfma_f32_16x16x32_bf16(wh, vv[c & 1][ks], acc[mt], 0, 0, 0);
                acc[mt] = __builtin_amdgcn_mfma_f32_16x16x32_bf16(wl, vv[c & 1][ks], acc[mt], 0, 0, 0);
            }
        }
        __builtin_amdgcn_s_setprio(0);

        // (4) gelu + pack + vt store (keep packed words for the transpose)
        uint2 w[4];
        #pragma unroll
        for (int mt = 0; mt < 4; ++mt) {
            w[mt].x = pk2bf(gelu_f(acc[mt][0]), gelu_f(acc[mt][1]));
            w[mt].y = pk2bf(gelu_f(acc[mt][2]), gelu_f(acc[mt][3]));
            *(uint2*)(vst + (size_t)c * 4096 + mt * 16 + quad * 4) = w[mt];
        }
        // (5) scatter transposed into trans[ch][y]: thread owns y = n2b,
        //     ch = mt*16 + quad*4 + r
        #pragma unroll
        for (int mt = 0; mt < 4; ++mt) {
            int chb = mt * 16 + quad * 4;
            trans[(chb + 0) * VS1 + n2b] = (ushort_t)(w[mt].x & 0xffffu);
            trans[(chb + 1) * VS1 + n2b] = (ushort_t)(w[mt].x >> 16);
            trans[(chb + 2) * VS1 + n2b] = (ushort_t)(w[mt].y & 0xffffu);
            trans[(chb + 3) * VS1 + n2b] = (ushort_t)(w[mt].y >> 16);
        }
        __builtin_amdgcn_sched_barrier(0);
        // (6) waits: scatter retired; t1s complete (vmcnt in-order: 10 newer
        //     ops = pf 6 + stores 4; last chunk has no pf -> 4)
        asm volatile("s_waitcnt lgkmcnt(0)" ::: "memory");
        if (c < 15) asm volatile("s_waitcnt vmcnt(10)" ::: "memory");
        else        asm volatile("s_waitcnt vmcnt(4)" ::: "memory");
        __builtin_amdgcn_sched_barrier(0);
        __builtin_amdgcn_s_barrier();   // barrier1: trans + t1s visible
        __builtin_amdgcn_sched_barrier(0);

        // (8) f1 MFMA: A = trans rows wv*16..+16, B = T1 chunk (swizzled slots)
        #pragma unroll
        for (int ys = 0; ys < 2; ++ys) {
            short8 af = *(const short8*)&trans[(wv * 16 + lm) * VS1 + ys * 32 + quad * 8];
            #pragma unroll
            for (int nt = 0; nt < 4; ++nt) {
                int sl = ((ys * 4 + quad) ^ r7) * 8;
                short8 bh = *(const short8*)&t1s[(nt * 16 + lm) * 64 + sl];
                short8 bl = *(const short8*)&t1s[4096 + (nt * 16 + lm) * 64 + sl];
                facc[nt] = __builtin_amdgcn_mfma_f32_16x16x32_bf16(af, bh, facc[nt], 0, 0, 0);
                facc[nt] = __builtin_amdgcn_mfma_f32_16x16x32_bf16(af, bl, facc[nt], 0, 0, 0);
            }
        }
        __builtin_amdgcn_sched_barrier(0);
        __builtin_amdgcn_s_barrier();   // barrier2: f1 reads done before rewrite
        __builtin_amdgcn_sched_barrier(0);
    }

    // ---- epilogue: gT row n1 (overwrites this block's own Bhl slot; WAR safe)
    float* grow = gT + (size_t)n1 * 4096;
    #pragma unroll
    for (int nt = 0; nt < 4; ++nt)
        #pragma unroll
        for (int r = 0; r < 4; ++r)
            grow[(wv * 16 + quad * 4 + r) * 64 + nt * 16 + lm] = facc[nt][r];
}

// ---------------- I2 final (R8 structure + fused projection; interleaved Bhl)
__global__ __launch_bounds__(256, 4) void k_i2fin(ushort_t* __restrict__ vt,
        const ushort_t* __restrict__ Bhl,
        const ushort_t* __restrict__ T2h, const ushort_t* __restrict__ T2l,
        const ushort_t* __restrict__ wTh, const ushort_t* __restrict__ wTl,
        const float* __restrict__ Wp, const float* __restrict__ bp,
        float* __restrict__ out) {
    __shared__ __align__(16) ushort_t ab[16384];
    int t = threadIdx.x;
    int wv = t >> 6, lane = t & 63;
    int lm = lane & 15, quad = lane >> 4;
    int n1 = blockIdx.x;
    const ushort_t* Bhr = Bhl + (size_t)n1 * 8192;
    const ushort_t* Blr = Bhr + 4096;
    {
        const ushort_t* s = (wv == 0) ? Bhr : (wv == 1) ? Blr : (wv == 2) ? wTh : wTl;
        #pragma unroll
        for (int i = 0; i < 8; ++i) {
            int j = i * 64 + lane;
            int r = j >> 3, u = (j & 7) ^ (r & 7);
            async16(&ab[wv * 4096 + i * 512], s + r * 64 + u * 8);
        }
    }
    int n2b = wv * 16 + lm;
    const ushort_t* t2hp = T2h + n2b * 64 + quad * 8;
    const ushort_t* t2lp = T2l + n2b * 64 + quad * 8;
    const ushort_t* vrd  = vt + ((size_t)n1 * 1024 + n2b) * 64 + quad * 8;
    short8 th[2][2], tl[2][2], vv[2][2];
    #pragma unroll
    for (int ks = 0; ks < 2; ++ks) {
        th[0][ks] = *(const short8*)(t2hp + ks * 32);
        tl[0][ks] = *(const short8*)(t2lp + ks * 32);
        vv[0][ks] = *(const short8*)(vrd + ks * 32);
    }
    float4 wpv[4];
    float bp0 = bp[0];
    #pragma unroll
    for (int mt = 0; mt < 4; ++mt) wpv[mt] = *(const float4*)&Wp[mt * 16 + quad * 4];
    __syncthreads();

    int r7 = lm & 7;
    #pragma unroll
    for (int c = 0; c < 16; ++c) {
        if (c < 15) {
            #pragma unroll
            for (int ks = 0; ks < 2; ++ks) {
                th[(c + 1) & 1][ks] = *(const short8*)(t2hp + (c + 1) * 4096 + ks * 32);
                tl[(c + 1) & 1][ks] = *(const short8*)(t2lp + (c + 1) * 4096 + ks * 32);
                vv[(c + 1) & 1][ks] = *(const short8*)(vrd + (size_t)(c + 1) * 4096 + ks * 32);
            }
        }
        __builtin_amdgcn_sched_barrier(0);
        floatx4 acc[4];
        #pragma unroll
        for (int mt = 0; mt < 4; ++mt) acc[mt] = (floatx4)(0.f);
        __builtin_amdgcn_s_setprio(1);
        #pragma unroll
        for (int ks = 0; ks < 2; ++ks) {
            int sl = ((ks * 4 + quad) ^ r7) * 8;
            #pragma unroll
            for (int mt = 0; mt < 4; ++mt) {
                int ro = (mt * 16 + lm) * 64 + sl;
                short8 ah = *(const short8*)&ab[ro];
                short8 al = *(const short8*)&ab[4096 + ro];
                short8 wh = *(const short8*)&ab[8192 + ro];
                short8 wl = *(const short8*)&ab[12288 + ro];
                acc[mt] = __builtin_amdgcn_mfma_f32_16x16x32_bf16(ah, th[c & 1][ks], acc[mt], 0, 0, 0);
                acc[mt] = __builtin_amdgcn_mfma_f32_16x16x32_bf16(al, th[c & 1][ks], acc[mt], 0, 0, 0);
                acc[mt] = __builtin_amdgcn_mfma_f32_16x16x32_bf16(ah, tl[c & 1][ks], acc[mt], 0, 0, 0);
                acc[mt] = __builtin_amdgcn_mfma_f32_16x16x32_bf16(wh, vv[c & 1][ks], acc[mt], 0, 0, 0);
                acc[mt] = __builtin_amdgcn_mfma_f32_16x16x32_bf16(wl, vv[c & 1][ks], acc[mt], 0, 0, 0);
            }
        }
        __builtin_amdgcn_s_setprio(0);
        float s = 0.f;
        #pragma unroll
        for (int mt = 0; mt < 4; ++mt) {
            s = fmaf(gelu_f(acc[mt][0]), wpv[mt].x, s);
            s = fmaf(gelu_f(acc[mt][1]), wpv[mt].y, s);
            s = fmaf(gelu_f(acc[mt][2]), wpv[mt].z, s);
            s = fmaf(gelu_f(acc[mt][3]), wpv[mt].w, s);
        }
        s += __shfl_xor(s, 16);
        s += __shfl_xor(s, 32);
        if (quad == 0)
            out[(size_t)n1 * 1024 + c * 64 + n2b] = s + bp0;
    }
}

extern "C" void kernel_launch(void* const* d_in, const int* in_sizes, int n_in,
                              void* d_out, int out_size, void* d_ws, size_t ws_size,
                              hipStream_t stream) {
    const float* in  = (const float*)d_in[0];
    const float* Wsh = (const float*)d_in[1];
    const float* bsh = (const float*)d_in[2];
    const float* Wp  = (const float*)d_in[15];
    const float* bp  = (const float*)d_in[16];

    // workspace layout (~151.9 MB, proven to fit)
    char* wsb = (char*)d_ws;
    ushort_t* vt   = (ushort_t*)wsb;                          // 134,217,728 B
    float* ctab = (float*)(wsb + 134217728);                  // 1024
    float* stab = ctab + 1024;                                // 1024
    float* gT   = stab + 1024;                                // 16 MB (rows interleave with Bhl)
    float* Rfr  = gT + 4194304;                               // 65536
    float* Rfi  = Rfr + 65536;                                // 65536
    ushort_t* T1h = (ushort_t*)(Rfi + 65536);                 // 64*1024
    ushort_t* T1l = T1h + 65536;
    ushort_t* T2h = T1l + 65536;                              // 1024*64
    ushort_t* T2l = T2h + 65536;
    ushort_t* wTh = T2l + 65536;                              // 4*64*64
    ushort_t* wTl = wTh + 16384;
    ushort_t* Bhl = (ushort_t*)gT;                            // interleaved with gT rows
    float* fpr = (float*)d_out;                               // alias d_out
    float* fpi = fpr + 524288;

    k_fill_tw<<<4, 256, 0, stream>>>(ctab, stab);
    k_fill_T1<<<256, 256, 0, stream>>>(T1h, T1l);
    k_fill_T2<<<256, 256, 0, stream>>>(T2h, T2l);
    k_fill_wT<<<dim3(16, 4), 256, 0, stream>>>((const float*)d_in[5], (const float*)d_in[8],
                                               (const float*)d_in[11], (const float*)d_in[14], wTh, wTl);
    k_shallow<<<65536, 256, 0, stream>>>(in, Wsh, bsh, vt);
    k_f1<<<512, 256, 0, stream>>>(vt, T1h, T1l, gT);          // layer-0 forward transform
    for (int L = 0; L < 4; ++L) {
        const float* Rr = (const float*)d_in[3 + L * 3];
        const float* Ri = (const float*)d_in[4 + L * 3];
        k_f2<<<dim3(8, 16, 4), 256, 0, stream>>>(gT, ctab, stab, fpr, fpi);
        k_mix<<<1024, 64, 0, stream>>>(fpr, fpi, Rr, Ri, Rfr, Rfi);
        k_i1<<<1024, 256, 0, stream>>>(Rfr, Rfi, ctab, stab, Bhl);
        if (L < 3) {
            // fused inverse + skip + NEXT layer's forward transform
            k_i2f<<<1024, 256, 0, stream>>>(vt, Bhl, T2h, T2l,
                    wTh + L * 4096, wTl + L * 4096, T1h, T1l, gT);
        } else {
            k_i2fin<<<1024, 256, 0, stream>>>(vt, Bhl, T2h, T2l,
                    wTh + L * 4096, wTl + L * 4096, Wp, bp, (float*)d_out);
        }
    }
}